// Round 1
// baseline (279.331 us; speedup 1.0000x reference)
//
#include <hip/hip_runtime.h>
#include <hip/hip_bf16.h>

// MFMA fragment types (guide-verified on gfx950: ext_vector_type(8) short for bf16x8)
typedef short short8 __attribute__((ext_vector_type(8)));
typedef float f32x4 __attribute__((ext_vector_type(4)));

union FragU { short8 v; unsigned u[4]; };

// pack two fp32 -> packed bf16 pair (RNE); should lower to v_cvt_pk_bf16_f32 on gfx950
__device__ inline unsigned pack2(float a, float b) {
    float2 f; f.x = a; f.y = b;
    __hip_bfloat162 h = __float22bfloat162_rn(f);
    union { __hip_bfloat162 h2; unsigned u; } cv;
    cv.h2 = h;
    return cv.u;
}

// One wave handles 16 b-values for one d. Within an iteration the wave evaluates
// 16 grid points (n = chunk*16 + lrow) of one b through the 64x64 layer via 8 MFMAs.
__global__ __launch_bounds__(256) void monotone_nn_kernel(
    const float* __restrict__ zin, const float* __restrict__ uin,
    const float* __restrict__ w01, const float* __restrict__ b01,
    const float* __restrict__ w02, const float* __restrict__ b02,
    const float* __restrict__ w03, const float* __restrict__ b03,
    const float* __restrict__ w11, const float* __restrict__ b11,
    const float* __restrict__ w12, const float* __restrict__ b12,
    const float* __restrict__ w13, const float* __restrict__ b13,
    const float* __restrict__ biasp, const int* __restrict__ lbp,
    float* __restrict__ out)
{
    const int tid  = threadIdx.x;
    const int lane = tid & 63;
    const int wave = tid >> 6;
    const int lrow = lane & 15;   // MFMA N-index (grid point within chunk) / A-row within tile
    const int quad = lane >> 4;

    const int wgid = blockIdx.x * 4 + wave;   // 0..4095
    const int d    = wgid & 1;
    const int b0   = (wgid >> 1) * 16;        // 16 b's per wave

    const float lb    = (float)lbp[0];
    const float biasv = biasp[0];

    const float* w1p = d ? w11 : w01;
    const float* b1p = d ? b11 : b01;
    const float* w2p = d ? w12 : w02;
    const float* b2p = d ? b12 : b02;
    const float* w3p = d ? w13 : w03;
    const float  b3  = (d ? b13 : b03)[0];

    // --- preload per-lane weight slices ---
    // layer-1: lane computes h1[h] for h = kc*32 + quad*8 + j
    float w1l[16], b1l[16];
    #pragma unroll
    for (int kc = 0; kc < 2; ++kc)
        #pragma unroll
        for (int j = 0; j < 8; ++j) {
            const int h = kc * 32 + quad * 8 + j;
            w1l[kc * 8 + j] = w1p[h];
            b1l[kc * 8 + j] = b1p[h];
        }

    // epilogue: lane holds h2 features f = t*16 + quad*4 + r
    float w3l[16], b2l[16];
    #pragma unroll
    for (int t = 0; t < 4; ++t)
        #pragma unroll
        for (int r = 0; r < 4; ++r) {
            const int f = t * 16 + quad * 4 + r;
            w3l[t * 4 + r] = w3p[f];
            b2l[t * 4 + r] = b2p[f];
        }

    // A-frags: A[f][h] = w2[f][h]; frag (t,kc): lane holds w2[t*16+lrow][kc*32+quad*8+j], j=0..7
    FragU afrag[8];
    #pragma unroll
    for (int t = 0; t < 4; ++t)
        #pragma unroll
        for (int kc = 0; kc < 2; ++kc) {
            const float* src = w2p + (t * 16 + lrow) * 64 + kc * 32 + quad * 8;
            #pragma unroll
            for (int jj = 0; jj < 4; ++jj)
                afrag[t * 2 + kc].u[jj] = pack2(src[2 * jj], src[2 * jj + 1]);
        }

    #pragma unroll 1
    for (int i = 0; i < 16; ++i) {
        const int b = b0 + i;
        const float zv = zin[b * 2 + d];
        const float ds = (fmaxf(zv, lb) - lb) * (1.0f / 127.0f);
        const float* ub = uin + (size_t)(b * 2 + d) * 127;
        float acc = 0.0f;

        #pragma unroll
        for (int c = 0; c < 8; ++c) {
            const int n = c * 16 + lrow;
            float uv;
            if (c < 7) uv = ub[n];
            else       uv = (lrow < 15) ? ub[n] : 0.0f;   // last grid point has no jitter
            // x = lb + ds*n + u*ds = fma(ds, n+u, lb)
            const float x = fmaf(ds, (float)n + uv, lb);

            // B-frag: h1[h] for this lane's n;  h = kc*32 + quad*8 + j
            FragU bfrag[2];
            #pragma unroll
            for (int kc = 0; kc < 2; ++kc) {
                float h1v[8];
                #pragma unroll
                for (int j = 0; j < 8; ++j) {
                    const float t0 = fmaf(x, w1l[kc * 8 + j], b1l[kc * 8 + j]);
                    h1v[j] = fmaxf(t0, 0.01f * t0);       // leaky_relu
                }
                #pragma unroll
                for (int jj = 0; jj < 4; ++jj)
                    bfrag[kc].u[jj] = pack2(h1v[2 * jj], h1v[2 * jj + 1]);
            }

            // D = W2 * H1 (+ b2 via acc init): 4 feature tiles x 2 K chunks
            f32x4 dacc[4];
            #pragma unroll
            for (int t = 0; t < 4; ++t) {
                f32x4 ci;
                ci[0] = b2l[t * 4 + 0]; ci[1] = b2l[t * 4 + 1];
                ci[2] = b2l[t * 4 + 2]; ci[3] = b2l[t * 4 + 3];
                ci = __builtin_amdgcn_mfma_f32_16x16x32_bf16(afrag[t * 2 + 0].v, bfrag[0].v, ci, 0, 0, 0);
                ci = __builtin_amdgcn_mfma_f32_16x16x32_bf16(afrag[t * 2 + 1].v, bfrag[1].v, ci, 0, 0, 0);
                dacc[t] = ci;
            }

            // epilogue: leaky(h2) . w3, reduce across quads, elu, accumulate (o+1)
            float p = 0.0f;
            #pragma unroll
            for (int t = 0; t < 4; ++t)
                #pragma unroll
                for (int r = 0; r < 4; ++r) {
                    const float h2 = dacc[t][r];
                    p = fmaf(fmaxf(h2, 0.01f * h2), w3l[t * 4 + r], p);
                }
            p += __shfl_xor(p, 16);
            p += __shfl_xor(p, 32);
            const float s = p + b3;
            // elu(s)+1 = s>0 ? s+1 : exp(s)
            const float e = __builtin_amdgcn_exp2f(s * 1.4426950408889634f);
            acc += (s > 0.0f) ? (s + 1.0f) : e;
        }

        // reduce the 16 per-n accumulators (quads already replicated)
        acc += __shfl_xor(acc, 1);
        acc += __shfl_xor(acc, 2);
        acc += __shfl_xor(acc, 4);
        acc += __shfl_xor(acc, 8);

        if (lane == 0) {
            float hz = acc * ds;
            if (d == 0) hz += biasv;   // bias added exactly once per b
            atomicAdd(out + b, hz);
        }
    }
}

extern "C" void kernel_launch(void* const* d_in, const int* in_sizes, int n_in,
                              void* d_out, int out_size, void* d_ws, size_t ws_size,
                              hipStream_t stream) {
    const float* z    = (const float*)d_in[0];
    const float* u    = (const float*)d_in[1];
    const float* w0_1 = (const float*)d_in[2];
    const float* b0_1 = (const float*)d_in[3];
    const float* w0_2 = (const float*)d_in[4];
    const float* b0_2 = (const float*)d_in[5];
    const float* w0_3 = (const float*)d_in[6];
    const float* b0_3 = (const float*)d_in[7];
    const float* w1_1 = (const float*)d_in[8];
    const float* b1_1 = (const float*)d_in[9];
    const float* w1_2 = (const float*)d_in[10];
    const float* b1_2 = (const float*)d_in[11];
    const float* w1_3 = (const float*)d_in[12];
    const float* b1_3 = (const float*)d_in[13];
    const float* bias = (const float*)d_in[14];
    const int*   lbp  = (const int*)d_in[16];

    // out is re-poisoned before every launch; zero it, then atomically accumulate.
    hipMemsetAsync(d_out, 0, (size_t)out_size * sizeof(float), stream);

    // 32768 b * 2 d / (16 b per wave) = 4096 waves = 1024 blocks of 4 waves
    monotone_nn_kernel<<<dim3(1024), dim3(256), 0, stream>>>(
        z, u, w0_1, b0_1, w0_2, b0_2, w0_3, b0_3,
        w1_1, b1_1, w1_2, b1_2, w1_3, b1_3,
        bias, lbp, (float*)d_out);
}

// Round 2
// 247.218 us; speedup vs baseline: 1.1299x; 1.1299x over previous
//
#include <hip/hip_runtime.h>
#include <hip/hip_bf16.h>

typedef short short8 __attribute__((ext_vector_type(8)));
typedef float f32x4 __attribute__((ext_vector_type(4)));

union FragU { short8 v; unsigned u[4]; };

// setup-path accurate pack (cost irrelevant, once per wave)
__device__ inline unsigned pack2_rne(float a, float b) {
    float2 f; f.x = a; f.y = b;
    __hip_bfloat162 h = __float22bfloat162_rn(f);
    union { __hip_bfloat162 h2; unsigned u; } cv; cv.h2 = h;
    return cv.u;
}

// hot-path pack: round-half-up to bf16 and merge with one v_perm_b32.
// D = {hi16(b+0x8000), hi16(a+0x8000)} -> low half = a (element 0), high = b.
__device__ inline unsigned pack2_fast(float a, float b) {
    union { float f; unsigned u; } ua, ub;
    ua.f = a; ub.f = b;
    return __builtin_amdgcn_perm(ub.u + 0x8000u, ua.u + 0x8000u, 0x07060302u);
}

// Block = 4 waves over 32 b's: wave w -> d = w&1, b-group = w>>1 (16 b's each).
// Within a wave-iteration the wave evaluates 16 grid points (n = c*16 + lrow)
// of one b through the 64x64 layer via 8 MFMAs; d=0/d=1 partial integrals are
// combined through LDS at the end (no atomics, no memset).
__global__ __launch_bounds__(256) void monotone_nn_kernel(
    const float* __restrict__ zin, const float* __restrict__ uin,
    const float* __restrict__ w01, const float* __restrict__ b01,
    const float* __restrict__ w02, const float* __restrict__ b02,
    const float* __restrict__ w03, const float* __restrict__ b03,
    const float* __restrict__ w11, const float* __restrict__ b11,
    const float* __restrict__ w12, const float* __restrict__ b12,
    const float* __restrict__ w13, const float* __restrict__ b13,
    const float* __restrict__ biasp, const int* __restrict__ lbp,
    float* __restrict__ out)
{
    __shared__ float lds_hz[4][16];

    const int tid  = threadIdx.x;
    const int lane = tid & 63;
    const int wave = tid >> 6;
    const int lrow = lane & 15;   // MFMA col index (grid point) / A-row within tile
    const int quad = lane >> 4;

    const int d  = wave & 1;
    const int bg = wave >> 1;
    const int b0 = blockIdx.x * 32 + bg * 16;   // 16 b's per wave

    const float lb    = (float)lbp[0];
    const float biasv = biasp[0];

    const float* w1p = d ? w11 : w01;
    const float* b1p = d ? b11 : b01;
    const float* w2p = d ? w12 : w02;
    const float* b2p = d ? b12 : b02;
    const float* w3p = d ? w13 : w03;
    const float  b3  = (d ? b13 : b03)[0];

    // --- preload per-lane weight slices ---
    // layer-1: lane computes h1[h] for h = kc*32 + quad*8 + j
    float w1l[16], b1l[16];
    #pragma unroll
    for (int kc = 0; kc < 2; ++kc)
        #pragma unroll
        for (int j = 0; j < 8; ++j) {
            const int h = kc * 32 + quad * 8 + j;
            w1l[kc * 8 + j] = w1p[h];
            b1l[kc * 8 + j] = b1p[h];
        }

    // epilogue: lane holds h2 features f = t*16 + quad*4 + r
    float w3l[16];
    f32x4 b2v[4];
    #pragma unroll
    for (int t = 0; t < 4; ++t)
        #pragma unroll
        for (int r = 0; r < 4; ++r) {
            const int f = t * 16 + quad * 4 + r;
            w3l[t * 4 + r] = w3p[f];
            b2v[t][r]      = b2p[f];      // persistent C operand for the MFMAs
        }

    // A-frags: A[f][h] = w2[f][h]; frag (t,kc): lane holds w2[t*16+lrow][kc*32+quad*8+j]
    FragU afrag[8];
    #pragma unroll
    for (int t = 0; t < 4; ++t)
        #pragma unroll
        for (int kc = 0; kc < 2; ++kc) {
            const float* src = w2p + (t * 16 + lrow) * 64 + kc * 32 + quad * 8;
            #pragma unroll
            for (int jj = 0; jj < 4; ++jj)
                afrag[t * 2 + kc].u[jj] = pack2_rne(src[2 * jj], src[2 * jj + 1]);
        }

    const float lrowf = (float)lrow;

    #pragma unroll 1
    for (int i = 0; i < 16; ++i) {
        const int b = b0 + i;
        const float zv = zin[b * 2 + d];
        const float ds = (fmaxf(zv, lb) - lb) * (1.0f / 127.0f);
        const float* ub = uin + (size_t)(b * 2 + d) * 127;
        float acc = 0.0f;

        #pragma unroll
        for (int c = 0; c < 8; ++c) {
            const int n = c * 16 + lrow;
            float uv;
            if (c < 7) uv = ub[n];
            else       uv = (lrow < 15) ? ub[n] : 0.0f;   // last grid point: no jitter
            const float x = fmaf(ds, lrowf + (float)(c * 16) + uv, lb);

            // B-frag: h1[h] for this lane's n; h = kc*32 + quad*8 + j
            FragU bfrag[2];
            #pragma unroll
            for (int kc = 0; kc < 2; ++kc) {
                #pragma unroll
                for (int jj = 0; jj < 4; ++jj) {
                    const float t0 = fmaf(x, w1l[kc * 8 + 2 * jj],     b1l[kc * 8 + 2 * jj]);
                    const float t1 = fmaf(x, w1l[kc * 8 + 2 * jj + 1], b1l[kc * 8 + 2 * jj + 1]);
                    const float r0 = fmaxf(t0, 0.01f * t0);
                    const float r1 = fmaxf(t1, 0.01f * t1);
                    bfrag[kc].u[jj] = pack2_fast(r0, r1);
                }
            }

            // h2 tile t, then consume immediately:
            // leaky(h)*w3 = 0.505*(h*w3) + 0.495*(|h|*w3); abs is a free VOP3 modifier
            float p1 = 0.0f, p2 = 0.0f;
            #pragma unroll
            for (int t = 0; t < 4; ++t) {
                f32x4 dacc;
                dacc = __builtin_amdgcn_mfma_f32_16x16x32_bf16(afrag[t * 2 + 0].v, bfrag[0].v, b2v[t], 0, 0, 0);
                dacc = __builtin_amdgcn_mfma_f32_16x16x32_bf16(afrag[t * 2 + 1].v, bfrag[1].v, dacc,   0, 0, 0);
                #pragma unroll
                for (int r = 0; r < 4; ++r) {
                    const float h2 = dacc[r];
                    p1 = fmaf(h2,        w3l[t * 4 + r], p1);
                    p2 = fmaf(fabsf(h2), w3l[t * 4 + r], p2);
                }
            }
            float p = fmaf(0.505f, p1, 0.495f * p2);
            p += __shfl_xor(p, 16);
            p += __shfl_xor(p, 32);
            const float s = p + b3;
            // elu(s)+1 = s>0 ? s+1 : exp(s)
            const float e = __builtin_amdgcn_exp2f(s * 1.4426950408889634f);
            acc += (s > 0.0f) ? (s + 1.0f) : e;
        }

        // reduce the 16 per-n accumulators (quads already replicated by the shuffles)
        acc += __shfl_xor(acc, 1);
        acc += __shfl_xor(acc, 2);
        acc += __shfl_xor(acc, 4);
        acc += __shfl_xor(acc, 8);

        if (lane == 0) lds_hz[wave][i] = acc * ds;
    }

    __syncthreads();
    if (tid < 32) {
        const int g = tid >> 4, l = tid & 15;
        out[blockIdx.x * 32 + g * 16 + l] = lds_hz[2 * g][l] + lds_hz[2 * g + 1][l] + biasv;
    }
}

extern "C" void kernel_launch(void* const* d_in, const int* in_sizes, int n_in,
                              void* d_out, int out_size, void* d_ws, size_t ws_size,
                              hipStream_t stream) {
    const float* z    = (const float*)d_in[0];
    const float* u    = (const float*)d_in[1];
    const float* w0_1 = (const float*)d_in[2];
    const float* b0_1 = (const float*)d_in[3];
    const float* w0_2 = (const float*)d_in[4];
    const float* b0_2 = (const float*)d_in[5];
    const float* w0_3 = (const float*)d_in[6];
    const float* b0_3 = (const float*)d_in[7];
    const float* w1_1 = (const float*)d_in[8];
    const float* b1_1 = (const float*)d_in[9];
    const float* w1_2 = (const float*)d_in[10];
    const float* b1_2 = (const float*)d_in[11];
    const float* w1_3 = (const float*)d_in[12];
    const float* b1_3 = (const float*)d_in[13];
    const float* bias = (const float*)d_in[14];
    const int*   lbp  = (const int*)d_in[16];

    // 32768 b * 2 d; each block covers 32 b's (4 waves: 2 b-groups x 2 d)
    monotone_nn_kernel<<<dim3(1024), dim3(256), 0, stream>>>(
        z, u, w0_1, b0_1, w0_2, b0_2, w0_3, b0_3,
        w1_1, b1_1, w1_2, b1_2, w1_3, b1_3,
        bias, lbp, (float*)d_out);
}

// Round 3
// 217.382 us; speedup vs baseline: 1.2850x; 1.1373x over previous
//
#include <hip/hip_runtime.h>
#include <hip/hip_bf16.h>

typedef _Float16 half2v __attribute__((ext_vector_type(2)));
typedef _Float16 half8  __attribute__((ext_vector_type(8)));
typedef float f32x4 __attribute__((ext_vector_type(4)));

union FragF16 { half8 v; half2v h[4]; };

// Block = 4 waves over 32 b's: wave w -> d = w&1, b-group = w>>1 (16 b's each).
// Per wave-iteration: 16 grid points (n = c*16 + lrow) of one b through the
// 64x64 layer via 8 f16 MFMAs. Layer-1 + leaky computed in packed fp16
// (v_pk_fma_f16 / v_pk_mul_f16 / v_pk_max_f16) -> result is directly the
// MFMA B-operand, no pack step. d=0/d=1 combined through LDS (no atomics).
__global__ __launch_bounds__(256) void monotone_nn_kernel(
    const float* __restrict__ zin, const float* __restrict__ uin,
    const float* __restrict__ w01, const float* __restrict__ b01,
    const float* __restrict__ w02, const float* __restrict__ b02,
    const float* __restrict__ w03, const float* __restrict__ b03,
    const float* __restrict__ w11, const float* __restrict__ b11,
    const float* __restrict__ w12, const float* __restrict__ b12,
    const float* __restrict__ w13, const float* __restrict__ b13,
    const float* __restrict__ biasp, const int* __restrict__ lbp,
    float* __restrict__ out)
{
    __shared__ float lds_hz[4][16];

    const int tid  = threadIdx.x;
    const int lane = tid & 63;
    const int wave = tid >> 6;
    const int lrow = lane & 15;   // MFMA col index (grid point) / A-row within tile
    const int quad = lane >> 4;

    const int d  = wave & 1;
    const int bg = wave >> 1;
    const int b0 = blockIdx.x * 32 + bg * 16;   // 16 b's per wave

    const float lb    = (float)lbp[0];
    const float biasv = biasp[0];

    const float* w1p = d ? w11 : w01;
    const float* b1p = d ? b11 : b01;
    const float* w2p = d ? w12 : w02;
    const float* b2p = d ? b12 : b02;
    const float* w3p = d ? w13 : w03;
    const float  b3  = (d ? b13 : b03)[0];

    // --- preload per-lane weight slices (setup; cost amortized over 128 c-iters) ---
    // layer-1 packed fp16: lane computes h1[h] for h = kc*32 + quad*8 + j,
    // pair (kc*4+jj) holds h = (2jj, 2jj+1) offsets -> lo = even k (MFMA k order)
    half2v w1pk[8], b1pk[8];
    #pragma unroll
    for (int kc = 0; kc < 2; ++kc)
        #pragma unroll
        for (int jj = 0; jj < 4; ++jj) {
            const int h = kc * 32 + quad * 8 + 2 * jj;
            half2v w, bb;
            w[0]  = (_Float16)w1p[h];     w[1]  = (_Float16)w1p[h + 1];
            bb[0] = (_Float16)b1p[h];     bb[1] = (_Float16)b1p[h + 1];
            w1pk[kc * 4 + jj] = w;
            b1pk[kc * 4 + jj] = bb;
        }

    // epilogue: lane holds h2 features f = t*16 + quad*4 + r
    float w3l[16];
    f32x4 b2v[4];
    #pragma unroll
    for (int t = 0; t < 4; ++t)
        #pragma unroll
        for (int r = 0; r < 4; ++r) {
            const int f = t * 16 + quad * 4 + r;
            w3l[t * 4 + r] = w3p[f];
            b2v[t][r]      = b2p[f];      // persistent C operand for the MFMAs
        }

    // A-frags (fp16): A[f][h] = w2[f][h]; frag (t,kc): w2[t*16+lrow][kc*32+quad*8+j]
    FragF16 afrag[8];
    #pragma unroll
    for (int t = 0; t < 4; ++t)
        #pragma unroll
        for (int kc = 0; kc < 2; ++kc) {
            const float* src = w2p + (t * 16 + lrow) * 64 + kc * 32 + quad * 8;
            #pragma unroll
            for (int j = 0; j < 8; ++j)
                afrag[t * 2 + kc].v[j] = (_Float16)src[j];
        }

    const float lrowf = (float)lrow;
    const half2v k001 = { (_Float16)0.01f, (_Float16)0.01f };

    #pragma unroll 1
    for (int i = 0; i < 16; ++i) {
        const int b = b0 + i;
        const float zv = zin[b * 2 + d];
        const float ds = (fmaxf(zv, lb) - lb) * (1.0f / 127.0f);
        const float* ub = uin + (size_t)(b * 2 + d) * 127;
        float acc = 0.0f;

        #pragma unroll
        for (int c = 0; c < 8; ++c) {
            const int n = c * 16 + lrow;
            float uv;
            if (c < 7) uv = ub[n];
            else       uv = (lrow < 15) ? ub[n] : 0.0f;   // last grid point: no jitter
            const float x = fmaf(ds, lrowf + (float)(c * 16) + uv, lb);

            // broadcast x into a packed fp16 pair
            const _Float16 xh = (_Float16)x;
            const half2v x2 = { xh, xh };

            // B-frag: h1 = pk_max(t, 0.01*t), t = pk_fma(x2, w1, b1)
            FragF16 bfrag[2];
            #pragma unroll
            for (int kc = 0; kc < 2; ++kc)
                #pragma unroll
                for (int jj = 0; jj < 4; ++jj) {
                    const half2v t0 = x2 * w1pk[kc * 4 + jj] + b1pk[kc * 4 + jj];
                    bfrag[kc].h[jj] = __builtin_elementwise_max(t0, t0 * k001);
                }

            // h2 tile t, consumed immediately:
            // leaky(h)*w3 = 0.505*(h*w3) + 0.495*(|h|*w3); abs is a free VOP3 modifier
            float p1 = 0.0f, p2 = 0.0f;
            #pragma unroll
            for (int t = 0; t < 4; ++t) {
                f32x4 dacc;
                dacc = __builtin_amdgcn_mfma_f32_16x16x32_f16(afrag[t * 2 + 0].v, bfrag[0].v, b2v[t], 0, 0, 0);
                dacc = __builtin_amdgcn_mfma_f32_16x16x32_f16(afrag[t * 2 + 1].v, bfrag[1].v, dacc,   0, 0, 0);
                #pragma unroll
                for (int r = 0; r < 4; ++r) {
                    const float h2 = dacc[r];
                    p1 = fmaf(h2,        w3l[t * 4 + r], p1);
                    p2 = fmaf(fabsf(h2), w3l[t * 4 + r], p2);
                }
            }
            float p = fmaf(0.505f, p1, 0.495f * p2);
            p += __shfl_xor(p, 16);
            p += __shfl_xor(p, 32);
            const float s = p + b3;
            // elu(s)+1 = s>0 ? s+1 : exp(s)
            const float e = __builtin_amdgcn_exp2f(s * 1.4426950408889634f);
            acc += (s > 0.0f) ? (s + 1.0f) : e;
        }

        // reduce the 16 per-n accumulators (quads already replicated by the shuffles)
        acc += __shfl_xor(acc, 1);
        acc += __shfl_xor(acc, 2);
        acc += __shfl_xor(acc, 4);
        acc += __shfl_xor(acc, 8);

        if (lane == 0) lds_hz[wave][i] = acc * ds;
    }

    __syncthreads();
    if (tid < 32) {
        const int g = tid >> 4, l = tid & 15;
        out[blockIdx.x * 32 + g * 16 + l] = lds_hz[2 * g][l] + lds_hz[2 * g + 1][l] + biasv;
    }
}

extern "C" void kernel_launch(void* const* d_in, const int* in_sizes, int n_in,
                              void* d_out, int out_size, void* d_ws, size_t ws_size,
                              hipStream_t stream) {
    const float* z    = (const float*)d_in[0];
    const float* u    = (const float*)d_in[1];
    const float* w0_1 = (const float*)d_in[2];
    const float* b0_1 = (const float*)d_in[3];
    const float* w0_2 = (const float*)d_in[4];
    const float* b0_2 = (const float*)d_in[5];
    const float* w0_3 = (const float*)d_in[6];
    const float* b0_3 = (const float*)d_in[7];
    const float* w1_1 = (const float*)d_in[8];
    const float* b1_1 = (const float*)d_in[9];
    const float* w1_2 = (const float*)d_in[10];
    const float* b1_2 = (const float*)d_in[11];
    const float* w1_3 = (const float*)d_in[12];
    const float* b1_3 = (const float*)d_in[13];
    const float* bias = (const float*)d_in[14];
    const int*   lbp  = (const int*)d_in[16];

    // 32768 b * 2 d; each block covers 32 b's (4 waves: 2 b-groups x 2 d)
    monotone_nn_kernel<<<dim3(1024), dim3(256), 0, stream>>>(
        z, u, w0_1, b0_1, w0_2, b0_2, w0_3, b0_3,
        w1_1, b1_1, w1_2, b1_2, w1_3, b1_3,
        bias, lbp, (float*)d_out);
}